// Round 14
// baseline (227.700 us; speedup 1.0000x reference)
//
#include <hip/hip_runtime.h>
#include <hip/hip_bf16.h>
#include <math.h>

// B=4, K=4, L=512, H=16, D=64, HID=1024, MAXPOS=512

typedef __attribute__((ext_vector_type(8))) short short8;
typedef __attribute__((ext_vector_type(4))) float f32x4;

#define MFMA_BF16(a,b,c) __builtin_amdgcn_mfma_f32_16x16x32_bf16((a),(b),(c),0,0,0)
#define GLL16(gp, lp) __builtin_amdgcn_global_load_lds( \
    (const __attribute__((address_space(1))) void*)(gp), \
    (__attribute__((address_space(3))) void*)(lp), 16, 0, 0)

#define SQRT_BETA 0.4246608995262131f   // sqrt(log2(e)/8)
#define LOG2E     1.4426950408889634f

static __device__ __forceinline__ unsigned short f2bf(float x) {
    unsigned int u = __builtin_bit_cast(unsigned int, x);
    u += 0x7fffu + ((u >> 16) & 1u);     // round-to-nearest-even
    return (unsigned short)(u >> 16);
}
static __device__ __forceinline__ float bf2f(unsigned short u) {
    unsigned int v = ((unsigned int)u) << 16;
    return __builtin_bit_cast(float, v);
}
static __device__ __forceinline__ unsigned cvt_pk_bf16(float lo, float hi) {
    unsigned r;
    asm("v_cvt_pk_bf16_f32 %0, %1, %2" : "=v"(r) : "v"(lo), "v"(hi));
    return r;
}
static __device__ __forceinline__ float exp2_fast(float x) {
    float r;
    asm("v_exp_f32 %0, %1" : "=v"(r) : "v"(x));
    return r;
}

// ---------------------------------------------------------------- fused converts
// entry 6 (dist_emb): XOR-swizzled 16B-unit order + pre-scaled by sqrt(beta).
struct CvtArgs {
    const float* s[7];
    unsigned short* d[7];
    int n4[7];
    float scale[7];
};
__global__ void cvt_all(CvtArgs a) {
#pragma unroll 1
    for (int k = 0; k < 7; k++) {
        const float4* s = (const float4*)a.s[k];
        ushort4* d = (ushort4*)a.d[k];
        const int n = a.n4[k];
        const float sc = a.scale[k];
        const bool swz = (k == 6);
        for (int i = blockIdx.x * 256 + threadIdx.x; i < n; i += gridDim.x * 256) {
            float4 v = s[i];
            ushort4 o;
            o.x = f2bf(v.x * sc); o.y = f2bf(v.y * sc);
            o.z = f2bf(v.z * sc); o.w = f2bf(v.w * sc);
            int di = i;
            if (swz) {
                int p = i >> 4, j = i & 15;
                di = p * 16 + (((j >> 1) ^ (p & 7)) * 2 + (j & 1));
            }
            d[di] = o;
        }
    }
}

// ---------------------------------------------------------------- GEMM 128x128, BK=32, prefetch dbuf
// O-projection: f32 out + residual.
__global__ __launch_bounds__(256, 3) void gemm128(
    const unsigned short* __restrict__ A,
    const unsigned short* __restrict__ W,
    const float* __restrict__ bias,
    const float* __restrict__ resid,
    float* __restrict__ outf)
{
    const int m0 = blockIdx.x * 128, n0 = blockIdx.y * 128;
    __shared__ unsigned short As[2][4096];
    __shared__ unsigned short Ws[2][4096];
    const int t = threadIdx.x, lane = t & 63, w = t >> 6;
    const int wr = w >> 1, wc = w & 1;
    const int c = lane & 15, g = lane >> 4;

    f32x4 acc[4][4];
#pragma unroll
    for (int i = 0; i < 4; i++)
#pragma unroll
        for (int j = 0; j < 4; j++) acc[i][j] = (f32x4)0.f;

    const size_t arow = (size_t)(m0 + (t >> 2)) * 1024 + (size_t)((t & 3) * 8);
    const size_t wrow = (size_t)(n0 + (t >> 2)) * 1024 + (size_t)((t & 3) * 8);

    GLL16(A + arow, &As[0][t * 8]);
    GLL16(A + arow + 64 * 1024, &As[0][t * 8 + 2048]);
    GLL16(W + wrow, &Ws[0][t * 8]);
    GLL16(W + wrow + 64 * 1024, &Ws[0][t * 8 + 2048]);
    __syncthreads();

    int cur = 0;
    for (int kt = 0; kt < 1024; kt += 32) {
        if (kt < 992) {
            GLL16(A + arow + kt + 32, &As[cur ^ 1][t * 8]);
            GLL16(A + arow + kt + 32 + 64 * 1024, &As[cur ^ 1][t * 8 + 2048]);
            GLL16(W + wrow + kt + 32, &Ws[cur ^ 1][t * 8]);
            GLL16(W + wrow + kt + 32 + 64 * 1024, &Ws[cur ^ 1][t * 8 + 2048]);
        }
        short8 af[4], bf_[4];
#pragma unroll
        for (int i = 0; i < 4; i++) af[i] = *(const short8*)&As[cur][(wr * 64 + i * 16 + c) * 32 + g * 8];
#pragma unroll
        for (int j = 0; j < 4; j++) bf_[j] = *(const short8*)&Ws[cur][(wc * 64 + j * 16 + c) * 32 + g * 8];
#pragma unroll
        for (int i = 0; i < 4; i++)
#pragma unroll
            for (int j = 0; j < 4; j++)
                acc[i][j] = MFMA_BF16(af[i], bf_[j], acc[i][j]);
        __syncthreads();
        cur ^= 1;
    }

#pragma unroll
    for (int i = 0; i < 4; i++)
#pragma unroll
        for (int j = 0; j < 4; j++) {
            int e = n0 + wc * 64 + j * 16 + c;
            float bv = bias[e];
#pragma unroll
            for (int ii = 0; ii < 4; ii++) {
                int m = m0 + wr * 64 + i * 16 + g * 4 + ii;
                outf[(size_t)m * 1024 + e] = acc[i][j][ii] + bv + resid[(size_t)m * 1024 + e];
            }
        }
}

// ---------------------------------------------------------------- Q+K+V projections, single-acc paths
// grid (144, 8): bx<64 -> K-proj; bx<128 -> V-proj; else Q-proj.
__global__ __launch_bounds__(256, 3) void gemm_qkv(
    const unsigned short* __restrict__ Ainj,  // [8192][1024]
    const unsigned short* __restrict__ Ahs,   // [2048][1024]
    const unsigned short* __restrict__ Wk,
    const unsigned short* __restrict__ Wv,
    const unsigned short* __restrict__ Wq,
    const float* __restrict__ biask,
    const float* __restrict__ biasv,
    const float* __restrict__ biasq,
    unsigned short* __restrict__ outK,       // [16][16][512][64] swizzled
    unsigned short* __restrict__ outV,       // [16][16][64][512] d-major
    unsigned short* __restrict__ outQ)       // [4][16][512][64] linear
{
    const int bx = blockIdx.x, n0 = blockIdx.y * 128;
    const int t = threadIdx.x, lane = t & 63, w = t >> 6;
    const int wr = w >> 1, wc = w & 1;
    const int c = lane & 15, g = lane >> 4;

    __shared__ unsigned short As[2][4096];
    __shared__ unsigned short Ws[2][4096];

    const unsigned short* A;
    const unsigned short* W;
    const float* bias;
    int m0, mode;
    if (bx < 64)       { A = Ainj; W = Wk; bias = biask; m0 = bx * 128;         mode = 0; }
    else if (bx < 128) { A = Ainj; W = Wv; bias = biasv; m0 = (bx - 64) * 128;  mode = 1; }
    else               { A = Ahs;  W = Wq; bias = biasq; m0 = (bx - 128) * 128; mode = 2; }

    f32x4 acc[4][4];
#pragma unroll
    for (int i = 0; i < 4; i++)
#pragma unroll
        for (int j = 0; j < 4; j++) acc[i][j] = (f32x4)0.f;

    const size_t arow = (size_t)(m0 + (t >> 2)) * 1024 + (size_t)((t & 3) * 8);
    const size_t wrow = (size_t)(n0 + (t >> 2)) * 1024 + (size_t)((t & 3) * 8);

    GLL16(A + arow, &As[0][t * 8]);
    GLL16(A + arow + 64 * 1024, &As[0][t * 8 + 2048]);
    GLL16(W + wrow, &Ws[0][t * 8]);
    GLL16(W + wrow + 64 * 1024, &Ws[0][t * 8 + 2048]);
    __syncthreads();

    int cur = 0;
    for (int kt = 0; kt < 1024; kt += 32) {
        if (kt < 992) {
            GLL16(A + arow + kt + 32, &As[cur ^ 1][t * 8]);
            GLL16(A + arow + kt + 32 + 64 * 1024, &As[cur ^ 1][t * 8 + 2048]);
            GLL16(W + wrow + kt + 32, &Ws[cur ^ 1][t * 8]);
            GLL16(W + wrow + kt + 32 + 64 * 1024, &Ws[cur ^ 1][t * 8 + 2048]);
        }
        short8 af[4], bf_[4];
#pragma unroll
        for (int i = 0; i < 4; i++) af[i] = *(const short8*)&As[cur][(wr * 64 + i * 16 + c) * 32 + g * 8];
#pragma unroll
        for (int j = 0; j < 4; j++) bf_[j] = *(const short8*)&Ws[cur][(wc * 64 + j * 16 + c) * 32 + g * 8];
#pragma unroll
        for (int i = 0; i < 4; i++)
#pragma unroll
            for (int j = 0; j < 4; j++)
                acc[i][j] = MFMA_BF16(af[i], bf_[j], acc[i][j]);
        __syncthreads();
        cur ^= 1;
    }

    if (mode == 0) {
#pragma unroll
        for (int i = 0; i < 4; i++)
#pragma unroll
            for (int j = 0; j < 4; j++) {
                int e = n0 + wc * 64 + j * 16 + c;
                float bv = bias[e];
                int hh = e >> 6, d = e & 63;
                int du = d >> 3, dl = d & 7;
#pragma unroll
                for (int ii = 0; ii < 4; ii++) {
                    int m = m0 + wr * 64 + i * 16 + g * 4 + ii;
                    int grp = m >> 9, l = m & 511;
                    int dd = (du ^ (l & 7)) * 8 + dl;
                    outK[(((size_t)grp * 16 + hh) * 512 + l) * 64 + dd] = f2bf((acc[i][j][ii] + bv) * SQRT_BETA);
                }
            }
    } else if (mode == 1) {
#pragma unroll
        for (int i = 0; i < 4; i++)
#pragma unroll
            for (int j = 0; j < 4; j++) {
                int e = n0 + wc * 64 + j * 16 + c;
                float bv = bias[e];
                int hh = e >> 6, d = e & 63;
                int mb = m0 + wr * 64 + i * 16 + g * 4;
                int grp = mb >> 9, l = mb & 511;
                ushort4 o;
                o.x = f2bf(acc[i][j][0] + bv);
                o.y = f2bf(acc[i][j][1] + bv);
                o.z = f2bf(acc[i][j][2] + bv);
                o.w = f2bf(acc[i][j][3] + bv);
                *(ushort4*)&outV[(((size_t)grp * 16 + hh) * 64 + d) * 512 + l] = o;
            }
    } else {
#pragma unroll
        for (int i = 0; i < 4; i++)
#pragma unroll
            for (int j = 0; j < 4; j++) {
                int e = n0 + wc * 64 + j * 16 + c;
                float bv = bias[e];
                int hh = e >> 6, d = e & 63;
#pragma unroll
                for (int ii = 0; ii < 4; ii++) {
                    int m = m0 + wr * 64 + i * 16 + g * 4 + ii;
                    int grp = m >> 9, l = m & 511;
                    outQ[(((size_t)grp * 16 + hh) * 512 + l) * 64 + d] = f2bf((acc[i][j][ii] + bv) * SQRT_BETA);
                }
            }
    }
}

// ---------------------------------------------------------------- attention
// r13 structure + T5 s_setprio around the MFMA clusters (3 independent
// blocks/CU at different phases -> priority lets compute waves preempt
// staging waves; m191-class mechanism).
__global__ __launch_bounds__(256, 3) void attn_kernel(
    const unsigned short* __restrict__ Qb,   // [4][16][512][64] *sqrt(beta)
    const unsigned short* __restrict__ Kbs,  // [16][16][512][64] unit-swizzled, *sqrt(beta)
    const unsigned short* __restrict__ Vtb,  // [16][16][64][512] d-major
    const unsigned short* __restrict__ dists,// [1024][64] unit-swizzled, *sqrt(beta)
    const float* __restrict__ mask,          // [16][512]
    unsigned short* __restrict__ ctxb)       // [16][512][1024] bf16
{
    // XCD-aware decode: all 8 l-tiles of one (h,bk) on one XCD
    const int dspt = blockIdx.x;
    const int xcd = dspt & 7, idx = dspt >> 3;
    const int pair = xcd * 32 + (idx >> 3);
    const int lt = idx & 7;
    const int h = pair >> 4, bk = pair & 15;
    const int l0 = lt * 64;
    const int b = bk >> 2;                   // repeat_interleave(q, 4)

    __shared__ unsigned char smem[34304];
    unsigned short* KsU = (unsigned short*)smem;            // [64][64] swizzled units
    unsigned short* DsU = (unsigned short*)(smem + 8192);   // [128][64] swizzled units
    float* KDs = (float*)smem;                              // [64][84] f32 band (alias!)
    unsigned short* Ps = (unsigned short*)(smem + 24576);   // [64][76] bf16 probs

    const int t = threadIdx.x, lane = t & 63, w = t >> 6;
    const int c = lane & 15, g = lane >> 4;
    const int xsw  = (g ^ (c & 7)) * 8;          // swizzled elem offset, unit g
    const int xsw4 = ((g + 4) ^ (c & 7)) * 8;    // unit g+4

    const unsigned short* Qg = Qb  + ((size_t)(b  * 16 + h) * 512) * 64;
    const unsigned short* Kg = Kbs + ((size_t)(bk * 16 + h) * 512) * 64;
    const unsigned short* Vg = Vtb + ((size_t)(bk * 16 + h) * 64) * 512;

    // Q fragments hoisted (pre-scaled)
    short8 aq0 = *(const short8*)&Qg[(size_t)(l0 + w * 16 + c) * 64 + g * 8];
    short8 aq1 = *(const short8*)&Qg[(size_t)(l0 + w * 16 + c) * 64 + 32 + g * 8];

    // QD-gather constants (tile-invariant)
    int bpa[4];
    bool selb[4];
#pragma unroll
    for (int i = 0; i < 4; i++) {
        int cp = (g * 4 + i - c + 15) & 15;
        bpa[i] = (g * 16 + cp) * 4;
        selb[i] = (g * 4 + i) > c;
    }

    float s_part[4];
    f32x4 acc_o[4];
#pragma unroll
    for (int i = 0; i < 4; i++) { s_part[i] = 0.f; acc_o[i] = (f32x4)0.f; }

    for (int r0 = 0; r0 < 512; r0 += 64) {
        const int pbase = l0 - r0 + 448;        // dist window start in [0, 896]
        __syncthreads();                        // (1) prev-tile KD/P/PV reads done

        // stage K (2 glls) + dist window (4 glls)
        GLL16(Kg + (size_t)(r0 + w * 16) * 64 + lane * 8,     KsU + (w * 16) * 64 + lane * 8);
        GLL16(Kg + (size_t)(r0 + w * 16 + 8) * 64 + lane * 8, KsU + (w * 16 + 8) * 64 + lane * 8);
        const unsigned short* dsrc = dists + (size_t)pbase * 64;
#pragma unroll
        for (int j = 0; j < 4; j++)
            GLL16(dsrc + (size_t)(w * 32 + j * 8) * 64 + lane * 8,
                  DsU + (w * 32 + j * 8) * 64 + lane * 8);
        // mask (folded into S1 acc init); drained by barrier (2)'s vmcnt
        const float* mrow = mask + (size_t)bk * 512 + r0;
        float mv2[4];
#pragma unroll
        for (int f = 0; f < 4; f++) mv2[f] = mrow[f * 16 + c] * LOG2E;
        __syncthreads();                        // (2) staging visible

        // fragment reads: K (8 b128) and dist (10 b128)
        short8 bkf0[4], bkf1[4];
#pragma unroll
        for (int f = 0; f < 4; f++) {
            bkf0[f] = *(const short8*)&KsU[(f * 16 + c) * 64 + xsw];
            bkf1[f] = *(const short8*)&KsU[(f * 16 + c) * 64 + xsw4];
        }
        short8 dq0[5], dq1[5];
#pragma unroll
        for (int q5 = 0; q5 < 5; q5++) {
            dq0[q5] = *(const short8*)&DsU[((w + q5) * 16 + c) * 64 + xsw];
            dq1[q5] = *(const short8*)&DsU[((w + q5) * 16 + c) * 64 + xsw4];
        }
        __syncthreads();                        // (2b) staging dead -> KDs alias safe

        // ---- MFMA cluster 1: S1 + QD + KD (T5 priority) ----
        __builtin_amdgcn_s_setprio(1);
        // S1 = QK^T with mask-init accumulator
        f32x4 s_acc[4];
#pragma unroll
        for (int f = 0; f < 4; f++) {
            f32x4 z = {mv2[f], mv2[f], mv2[f], mv2[f]};
            z = MFMA_BF16(aq0, bkf0[f], z);
            s_acc[f] = MFMA_BF16(aq1, bkf1[f], z);
        }
        // QD: 5 frags, in registers
        f32x4 aQ[5];
#pragma unroll
        for (int q5 = 0; q5 < 5; q5++) {
            f32x4 z = (f32x4)0.f;
            z = MFMA_BF16(aq0, dq0[q5], z);
            aQ[q5] = MFMA_BF16(aq1, dq1[q5], z);
        }
        // KD transposed (f-corrected): band row 16f+c, bucket j from dist frag
        // (3-f+j) at compact col (w+j)*16 -> read col recovers rel row for all f.
#pragma unroll
        for (int f = 0; f < 4; f++)
#pragma unroll
            for (int j = 0; j < 2; j++) {
                const int q = 3 - f + j;
                f32x4 aK = (f32x4)0.f;
                aK = MFMA_BF16(dq0[q], bkf0[f], aK);
                aK = MFMA_BF16(dq1[q], bkf1[f], aK);
                *(f32x4*)&KDs[(16 * f + c) * 84 + (w + j) * 16 + g * 4] = aK;
            }
        __builtin_amdgcn_s_setprio(0);

        // V loads (global, consumed in PV -> latency hidden)
        short8 vfr[4][2];
#pragma unroll
        for (int n = 0; n < 4; n++)
#pragma unroll
            for (int j = 0; j < 2; j++)
                vfr[n][j] = *(const short8*)&Vg[(size_t)(n * 16 + c) * 512 + r0 + j * 32 + g * 8];

        // QD gather: 20 bpermute + cndmask select
        int bp[5][4];
#pragma unroll
        for (int q5 = 0; q5 < 5; q5++)
#pragma unroll
            for (int i = 0; i < 4; i++)
                bp[q5][i] = __builtin_amdgcn_ds_bpermute(bpa[i], __builtin_bit_cast(int, aQ[q5][i]));

        // assembly: exp2(s1 + qd + kd), accumulate denominator
        float pv[4][4];
#pragma unroll
        for (int f = 0; f < 4; f++) {
            const float* kdb = &KDs[(16 * f + c) * 84 + w * 16 + g * 4 - c + 15];
#pragma unroll
            for (int i = 0; i < 4; i++) {
                float kd = kdb[i];
                float qd = __builtin_bit_cast(float, selb[i] ? bp[4 - f][i] : bp[3 - f][i]);
                float pe = exp2_fast(s_acc[f][i] + qd + kd);
                pv[f][i] = pe;
                s_part[i] += pe;
            }
        }
        // P -> LDS (own rows only)
#pragma unroll
        for (int f = 0; f < 4; f += 2)
#pragma unroll
            for (int i = 0; i < 4; i++) {
                unsigned pk2 = cvt_pk_bf16(pv[f][i], pv[f + 1][i]);
                const int row = (w * 16 + g * 4 + i) * 76;
                Ps[row + f * 16 + c] = (unsigned short)pk2;
                Ps[row + (f + 1) * 16 + c] = (unsigned short)(pk2 >> 16);
            }

        // ---- MFMA cluster 2: PV (T5 priority) ----
        __builtin_amdgcn_s_setprio(1);
#pragma unroll
        for (int j = 0; j < 2; j++) {
            short8 ap = *(const short8*)&Ps[(w * 16 + c) * 76 + j * 32 + g * 8];
#pragma unroll
            for (int n = 0; n < 4; n++)
                acc_o[n] = MFMA_BF16(ap, vfr[n][j], acc_o[n]);
        }
        __builtin_amdgcn_s_setprio(0);
    }

    // finalize: cross-lane denom reduce, then ctx[bk][l][h*64+d] = O/s
#pragma unroll
    for (int off = 1; off < 16; off <<= 1)
#pragma unroll
        for (int i = 0; i < 4; i++) s_part[i] += __shfl_xor(s_part[i], off);
#pragma unroll
    for (int i = 0; i < 4; i++) {
        float inv = 1.0f / s_part[i];
        int ll = w * 16 + g * 4 + i;
        unsigned short* dst = ctxb + ((size_t)bk * 512 + l0 + ll) * 1024 + h * 64;
#pragma unroll
        for (int n = 0; n < 4; n++) dst[n * 16 + c] = f2bf(acc_o[n][i] * inv);
    }
}

// ---------------------------------------------------------------- average over k (bf16)
__global__ void avg_kernel(const unsigned short* __restrict__ ctx, unsigned short* __restrict__ avgb) {
    int i = blockIdx.x * 256 + threadIdx.x;     // ushort4 index over [2048][256]
    if (i >= 2048 * 256) return;
    int e4 = i & 255, bl = i >> 8;
    int b = bl >> 9, l = bl & 511;
    size_t base = ((size_t)(b * 4) * 512 + l) * 256 + e4;
    const ushort4* cv = (const ushort4*)ctx;
    float s0 = 0.f, s1 = 0.f, s2 = 0.f, s3 = 0.f;
#pragma unroll
    for (int j = 0; j < 4; j++) {
        ushort4 v = cv[base + (size_t)j * 512 * 256];
        s0 += bf2f(v.x); s1 += bf2f(v.y); s2 += bf2f(v.z); s3 += bf2f(v.w);
    }
    ushort4 o;
    o.x = f2bf(s0 * 0.25f); o.y = f2bf(s1 * 0.25f);
    o.z = f2bf(s2 * 0.25f); o.w = f2bf(s3 * 0.25f);
    ((ushort4*)avgb)[i] = o;
}

// ---------------------------------------------------------------- LayerNorm rows of 1024 (in-place)
__global__ __launch_bounds__(256) void ln_kernel(float* __restrict__ x,
                                                 const float* __restrict__ gamma,
                                                 const float* __restrict__ beta) {
    const int row = blockIdx.x, t = threadIdx.x;
    float* xr = x + (size_t)row * 1024;
    float v[4], s = 0.f, sq = 0.f;
#pragma unroll
    for (int j = 0; j < 4; j++) { v[j] = xr[t + j * 256]; s += v[j]; sq += v[j] * v[j]; }
#pragma unroll
    for (int off = 1; off < 64; off <<= 1) { s += __shfl_xor(s, off); sq += __shfl_xor(sq, off); }
    __shared__ float ss[4], ssq[4];
    if ((t & 63) == 0) { ss[t >> 6] = s; ssq[t >> 6] = sq; }
    __syncthreads();
    s = ss[0] + ss[1] + ss[2] + ss[3];
    sq = ssq[0] + ssq[1] + ssq[2] + ssq[3];
    float mu = s * (1.f / 1024.f);
    float var = fmaxf(sq * (1.f / 1024.f) - mu * mu, 0.f);
    float inv = 1.0f / sqrtf(var + 1e-12f);
#pragma unroll
    for (int j = 0; j < 4; j++) {
        int e = t + j * 256;
        xr[e] = gamma[e] * (v[j] - mu) * inv + beta[e];
    }
}

// ---------------------------------------------------------------- launch
extern "C" void kernel_launch(void* const* d_in, const int* in_sizes, int n_in,
                              void* d_out, int out_size, void* d_ws, size_t ws_size,
                              hipStream_t stream) {
    const float* hs    = (const float*)d_in[0];
    const float* inj   = (const float*)d_in[1];
    const float* maskp = (const float*)d_in[2];
    const float* Wq    = (const float*)d_in[3];
    const float* bq    = (const float*)d_in[4];
    const float* Wk    = (const float*)d_in[5];
    const float* bk_   = (const float*)d_in[6];
    const float* Wv    = (const float*)d_in[7];
    const float* bv    = (const float*)d_in[8];
    const float* de    = (const float*)d_in[9];
    const float* Wo    = (const float*)d_in[10];
    const float* bo    = (const float*)d_in[11];
    const float* ln_g  = (const float*)d_in[12];
    const float* ln_b  = (const float*)d_in[13];
    float* out = (float*)d_out;
    (void)in_sizes; (void)n_in; (void)out_size; (void)ws_size;

    unsigned char* p = (unsigned char*)d_ws;
    auto take = [&](size_t bytes) {
        unsigned char* r = p;
        p += (bytes + 255) & ~(size_t)255;
        return r;
    };
    unsigned short* hsb   = (unsigned short*)take(2048ull * 1024 * 2);
    unsigned short* injb  = (unsigned short*)take(8192ull * 1024 * 2);
    unsigned short* Wqb   = (unsigned short*)take(1024ull * 1024 * 2);
    unsigned short* Wkb   = (unsigned short*)take(1024ull * 1024 * 2);
    unsigned short* Wvb   = (unsigned short*)take(1024ull * 1024 * 2);
    unsigned short* Wob   = (unsigned short*)take(1024ull * 1024 * 2);
    unsigned short* dists = (unsigned short*)take(1024ull * 64 * 2);   // row 1023 = pad
    unsigned short* Qbuf  = (unsigned short*)take(4ull * 16 * 512 * 64 * 2);
    unsigned short* Kbufs = (unsigned short*)take(16ull * 16 * 512 * 64 * 2);
    unsigned short* Vtb   = (unsigned short*)take(16ull * 16 * 64 * 512 * 2);
    unsigned short* ctxb  = (unsigned short*)take(16ull * 512 * 1024 * 2);
    unsigned short* avgb  = (unsigned short*)take(2048ull * 1024 * 2);

    // fused f32 -> bf16 converts (dist swizzled + sqrt(beta)-scaled)
    CvtArgs ca;
    ca.s[0] = hs;  ca.d[0] = hsb;   ca.n4[0] = 2048 * 256; ca.scale[0] = 1.f;
    ca.s[1] = inj; ca.d[1] = injb;  ca.n4[1] = 8192 * 256; ca.scale[1] = 1.f;
    ca.s[2] = Wq;  ca.d[2] = Wqb;   ca.n4[2] = 1024 * 256; ca.scale[2] = 1.f;
    ca.s[3] = Wk;  ca.d[3] = Wkb;   ca.n4[3] = 1024 * 256; ca.scale[3] = 1.f;
    ca.s[4] = Wv;  ca.d[4] = Wvb;   ca.n4[4] = 1024 * 256; ca.scale[4] = 1.f;
    ca.s[5] = Wo;  ca.d[5] = Wob;   ca.n4[5] = 1024 * 256; ca.scale[5] = 1.f;
    ca.s[6] = de;  ca.d[6] = dists; ca.n4[6] = 1023 * 16;  ca.scale[6] = SQRT_BETA;
    cvt_all<<<2048, 256, 0, stream>>>(ca);

    // Q+K+V projections: three single-acc 128^2 GEMM paths, 3 blocks/CU
    gemm_qkv<<<dim3(144, 8), 256, 0, stream>>>(injb, hsb, Wkb, Wvb, Wqb,
                                               bk_, bv, bq, Kbufs, Vtb, Qbuf);

    // attention (r13 structure + T5 setprio)
    attn_kernel<<<2048, 256, 0, stream>>>(Qbuf, Kbufs, Vtb, dists, maskp, ctxb);

    // average over k candidates
    avg_kernel<<<2048, 256, 0, stream>>>(ctxb, avgb);

    // output projection + bias + residual, then LayerNorm in-place on d_out
    gemm128<<<dim3(16, 8), 256, 0, stream>>>(avgb, Wob, bo, hs, out);
    ln_kernel<<<2048, 256, 0, stream>>>(out, ln_g, ln_b);
}

// Round 15
// 200.663 us; speedup vs baseline: 1.1347x; 1.1347x over previous
//
#include <hip/hip_runtime.h>
#include <hip/hip_bf16.h>
#include <math.h>

// B=4, K=4, L=512, H=16, D=64, HID=1024, MAXPOS=512

typedef __attribute__((ext_vector_type(8))) short short8;
typedef __attribute__((ext_vector_type(4))) float f32x4;

#define MFMA_BF16(a,b,c) __builtin_amdgcn_mfma_f32_16x16x32_bf16((a),(b),(c),0,0,0)
#define GLL16(gp, lp) __builtin_amdgcn_global_load_lds( \
    (const __attribute__((address_space(1))) void*)(gp), \
    (__attribute__((address_space(3))) void*)(lp), 16, 0, 0)

#define SQRT_BETA 0.4246608995262131f   // sqrt(log2(e)/8)
#define LOG2E     1.4426950408889634f

static __device__ __forceinline__ unsigned short f2bf(float x) {
    unsigned int u = __builtin_bit_cast(unsigned int, x);
    u += 0x7fffu + ((u >> 16) & 1u);     // round-to-nearest-even
    return (unsigned short)(u >> 16);
}
static __device__ __forceinline__ float bf2f(unsigned short u) {
    unsigned int v = ((unsigned int)u) << 16;
    return __builtin_bit_cast(float, v);
}
static __device__ __forceinline__ unsigned cvt_pk_bf16(float lo, float hi) {
    unsigned r;
    asm("v_cvt_pk_bf16_f32 %0, %1, %2" : "=v"(r) : "v"(lo), "v"(hi));
    return r;
}
static __device__ __forceinline__ float exp2_fast(float x) {
    float r;
    asm("v_exp_f32 %0, %1" : "=v"(r) : "v"(x));
    return r;
}

// ---------------------------------------------------------------- fused converts
// entry 6 (dist_emb): XOR-swizzled 16B-unit order + pre-scaled by sqrt(beta).
struct CvtArgs {
    const float* s[7];
    unsigned short* d[7];
    int n4[7];
    float scale[7];
};
__global__ void cvt_all(CvtArgs a) {
#pragma unroll 1
    for (int k = 0; k < 7; k++) {
        const float4* s = (const float4*)a.s[k];
        ushort4* d = (ushort4*)a.d[k];
        const int n = a.n4[k];
        const float sc = a.scale[k];
        const bool swz = (k == 6);
        for (int i = blockIdx.x * 256 + threadIdx.x; i < n; i += gridDim.x * 256) {
            float4 v = s[i];
            ushort4 o;
            o.x = f2bf(v.x * sc); o.y = f2bf(v.y * sc);
            o.z = f2bf(v.z * sc); o.w = f2bf(v.w * sc);
            int di = i;
            if (swz) {
                int p = i >> 4, j = i & 15;
                di = p * 16 + (((j >> 1) ^ (p & 7)) * 2 + (j & 1));
            }
            d[di] = o;
        }
    }
}

// ---------------------------------------------------------------- GEMM 128x128, BK=32, prefetch dbuf
// O-projection: f32 out + residual.
__global__ __launch_bounds__(256, 3) void gemm128(
    const unsigned short* __restrict__ A,
    const unsigned short* __restrict__ W,
    const float* __restrict__ bias,
    const float* __restrict__ resid,
    float* __restrict__ outf)
{
    const int m0 = blockIdx.x * 128, n0 = blockIdx.y * 128;
    __shared__ unsigned short As[2][4096];
    __shared__ unsigned short Ws[2][4096];
    const int t = threadIdx.x, lane = t & 63, w = t >> 6;
    const int wr = w >> 1, wc = w & 1;
    const int c = lane & 15, g = lane >> 4;

    f32x4 acc[4][4];
#pragma unroll
    for (int i = 0; i < 4; i++)
#pragma unroll
        for (int j = 0; j < 4; j++) acc[i][j] = (f32x4)0.f;

    const size_t arow = (size_t)(m0 + (t >> 2)) * 1024 + (size_t)((t & 3) * 8);
    const size_t wrow = (size_t)(n0 + (t >> 2)) * 1024 + (size_t)((t & 3) * 8);

    GLL16(A + arow, &As[0][t * 8]);
    GLL16(A + arow + 64 * 1024, &As[0][t * 8 + 2048]);
    GLL16(W + wrow, &Ws[0][t * 8]);
    GLL16(W + wrow + 64 * 1024, &Ws[0][t * 8 + 2048]);
    __syncthreads();

    int cur = 0;
    for (int kt = 0; kt < 1024; kt += 32) {
        if (kt < 992) {
            GLL16(A + arow + kt + 32, &As[cur ^ 1][t * 8]);
            GLL16(A + arow + kt + 32 + 64 * 1024, &As[cur ^ 1][t * 8 + 2048]);
            GLL16(W + wrow + kt + 32, &Ws[cur ^ 1][t * 8]);
            GLL16(W + wrow + kt + 32 + 64 * 1024, &Ws[cur ^ 1][t * 8 + 2048]);
        }
        short8 af[4], bf_[4];
#pragma unroll
        for (int i = 0; i < 4; i++) af[i] = *(const short8*)&As[cur][(wr * 64 + i * 16 + c) * 32 + g * 8];
#pragma unroll
        for (int j = 0; j < 4; j++) bf_[j] = *(const short8*)&Ws[cur][(wc * 64 + j * 16 + c) * 32 + g * 8];
#pragma unroll
        for (int i = 0; i < 4; i++)
#pragma unroll
            for (int j = 0; j < 4; j++)
                acc[i][j] = MFMA_BF16(af[i], bf_[j], acc[i][j]);
        __syncthreads();
        cur ^= 1;
    }

#pragma unroll
    for (int i = 0; i < 4; i++)
#pragma unroll
        for (int j = 0; j < 4; j++) {
            int e = n0 + wc * 64 + j * 16 + c;
            float bv = bias[e];
#pragma unroll
            for (int ii = 0; ii < 4; ii++) {
                int m = m0 + wr * 64 + i * 16 + g * 4 + ii;
                outf[(size_t)m * 1024 + e] = acc[i][j][ii] + bv + resid[(size_t)m * 1024 + e];
            }
        }
}

// ---------------------------------------------------------------- Q+K+V projections, single-acc paths
// grid (144, 8): bx<64 -> K-proj; bx<128 -> V-proj; else Q-proj.
__global__ __launch_bounds__(256, 3) void gemm_qkv(
    const unsigned short* __restrict__ Ainj,  // [8192][1024]
    const unsigned short* __restrict__ Ahs,   // [2048][1024]
    const unsigned short* __restrict__ Wk,
    const unsigned short* __restrict__ Wv,
    const unsigned short* __restrict__ Wq,
    const float* __restrict__ biask,
    const float* __restrict__ biasv,
    const float* __restrict__ biasq,
    unsigned short* __restrict__ outK,       // [16][16][512][64] swizzled
    unsigned short* __restrict__ outV,       // [16][16][64][512] d-major
    unsigned short* __restrict__ outQ)       // [4][16][512][64] linear
{
    const int bx = blockIdx.x, n0 = blockIdx.y * 128;
    const int t = threadIdx.x, lane = t & 63, w = t >> 6;
    const int wr = w >> 1, wc = w & 1;
    const int c = lane & 15, g = lane >> 4;

    __shared__ unsigned short As[2][4096];
    __shared__ unsigned short Ws[2][4096];

    const unsigned short* A;
    const unsigned short* W;
    const float* bias;
    int m0, mode;
    if (bx < 64)       { A = Ainj; W = Wk; bias = biask; m0 = bx * 128;         mode = 0; }
    else if (bx < 128) { A = Ainj; W = Wv; bias = biasv; m0 = (bx - 64) * 128;  mode = 1; }
    else               { A = Ahs;  W = Wq; bias = biasq; m0 = (bx - 128) * 128; mode = 2; }

    f32x4 acc[4][4];
#pragma unroll
    for (int i = 0; i < 4; i++)
#pragma unroll
        for (int j = 0; j < 4; j++) acc[i][j] = (f32x4)0.f;

    const size_t arow = (size_t)(m0 + (t >> 2)) * 1024 + (size_t)((t & 3) * 8);
    const size_t wrow = (size_t)(n0 + (t >> 2)) * 1024 + (size_t)((t & 3) * 8);

    GLL16(A + arow, &As[0][t * 8]);
    GLL16(A + arow + 64 * 1024, &As[0][t * 8 + 2048]);
    GLL16(W + wrow, &Ws[0][t * 8]);
    GLL16(W + wrow + 64 * 1024, &Ws[0][t * 8 + 2048]);
    __syncthreads();

    int cur = 0;
    for (int kt = 0; kt < 1024; kt += 32) {
        if (kt < 992) {
            GLL16(A + arow + kt + 32, &As[cur ^ 1][t * 8]);
            GLL16(A + arow + kt + 32 + 64 * 1024, &As[cur ^ 1][t * 8 + 2048]);
            GLL16(W + wrow + kt + 32, &Ws[cur ^ 1][t * 8]);
            GLL16(W + wrow + kt + 32 + 64 * 1024, &Ws[cur ^ 1][t * 8 + 2048]);
        }
        short8 af[4], bf_[4];
#pragma unroll
        for (int i = 0; i < 4; i++) af[i] = *(const short8*)&As[cur][(wr * 64 + i * 16 + c) * 32 + g * 8];
#pragma unroll
        for (int j = 0; j < 4; j++) bf_[j] = *(const short8*)&Ws[cur][(wc * 64 + j * 16 + c) * 32 + g * 8];
#pragma unroll
        for (int i = 0; i < 4; i++)
#pragma unroll
            for (int j = 0; j < 4; j++)
                acc[i][j] = MFMA_BF16(af[i], bf_[j], acc[i][j]);
        __syncthreads();
        cur ^= 1;
    }

    if (mode == 0) {
#pragma unroll
        for (int i = 0; i < 4; i++)
#pragma unroll
            for (int j = 0; j < 4; j++) {
                int e = n0 + wc * 64 + j * 16 + c;
                float bv = bias[e];
                int hh = e >> 6, d = e & 63;
                int du = d >> 3, dl = d & 7;
#pragma unroll
                for (int ii = 0; ii < 4; ii++) {
                    int m = m0 + wr * 64 + i * 16 + g * 4 + ii;
                    int grp = m >> 9, l = m & 511;
                    int dd = (du ^ (l & 7)) * 8 + dl;
                    outK[(((size_t)grp * 16 + hh) * 512 + l) * 64 + dd] = f2bf((acc[i][j][ii] + bv) * SQRT_BETA);
                }
            }
    } else if (mode == 1) {
#pragma unroll
        for (int i = 0; i < 4; i++)
#pragma unroll
            for (int j = 0; j < 4; j++) {
                int e = n0 + wc * 64 + j * 16 + c;
                float bv = bias[e];
                int hh = e >> 6, d = e & 63;
                int mb = m0 + wr * 64 + i * 16 + g * 4;
                int grp = mb >> 9, l = mb & 511;
                ushort4 o;
                o.x = f2bf(acc[i][j][0] + bv);
                o.y = f2bf(acc[i][j][1] + bv);
                o.z = f2bf(acc[i][j][2] + bv);
                o.w = f2bf(acc[i][j][3] + bv);
                *(ushort4*)&outV[(((size_t)grp * 16 + hh) * 64 + d) * 512 + l] = o;
            }
    } else {
#pragma unroll
        for (int i = 0; i < 4; i++)
#pragma unroll
            for (int j = 0; j < 4; j++) {
                int e = n0 + wc * 64 + j * 16 + c;
                float bv = bias[e];
                int hh = e >> 6, d = e & 63;
#pragma unroll
                for (int ii = 0; ii < 4; ii++) {
                    int m = m0 + wr * 64 + i * 16 + g * 4 + ii;
                    int grp = m >> 9, l = m & 511;
                    outQ[(((size_t)grp * 16 + hh) * 512 + l) * 64 + d] = f2bf((acc[i][j][ii] + bv) * SQRT_BETA);
                }
            }
    }
}

// ---------------------------------------------------------------- attention
// r13 proven kernel (96 us measured, total 200.8): GLL-staged K+dist, 3
// barriers/tile, f32 KD band (f-corrected compaction) aliasing staging after
// (2b), Ps dedicated. launch_bounds(256,3) -> VGPR 84, no spill. NO setprio
// (r14: -28% — priority inversion across barrier-coupled wave groups).
__global__ __launch_bounds__(256, 3) void attn_kernel(
    const unsigned short* __restrict__ Qb,   // [4][16][512][64] *sqrt(beta)
    const unsigned short* __restrict__ Kbs,  // [16][16][512][64] unit-swizzled, *sqrt(beta)
    const unsigned short* __restrict__ Vtb,  // [16][16][64][512] d-major
    const unsigned short* __restrict__ dists,// [1024][64] unit-swizzled, *sqrt(beta)
    const float* __restrict__ mask,          // [16][512]
    unsigned short* __restrict__ ctxb)       // [16][512][1024] bf16
{
    // XCD-aware decode: all 8 l-tiles of one (h,bk) on one XCD
    const int dspt = blockIdx.x;
    const int xcd = dspt & 7, idx = dspt >> 3;
    const int pair = xcd * 32 + (idx >> 3);
    const int lt = idx & 7;
    const int h = pair >> 4, bk = pair & 15;
    const int l0 = lt * 64;
    const int b = bk >> 2;                   // repeat_interleave(q, 4)

    __shared__ unsigned char smem[34304];
    unsigned short* KsU = (unsigned short*)smem;            // [64][64] swizzled units
    unsigned short* DsU = (unsigned short*)(smem + 8192);   // [128][64] swizzled units
    float* KDs = (float*)smem;                              // [64][84] f32 band (alias!)
    unsigned short* Ps = (unsigned short*)(smem + 24576);   // [64][76] bf16 probs

    const int t = threadIdx.x, lane = t & 63, w = t >> 6;
    const int c = lane & 15, g = lane >> 4;
    const int xsw  = (g ^ (c & 7)) * 8;          // swizzled elem offset, unit g
    const int xsw4 = ((g + 4) ^ (c & 7)) * 8;    // unit g+4

    const unsigned short* Qg = Qb  + ((size_t)(b  * 16 + h) * 512) * 64;
    const unsigned short* Kg = Kbs + ((size_t)(bk * 16 + h) * 512) * 64;
    const unsigned short* Vg = Vtb + ((size_t)(bk * 16 + h) * 64) * 512;

    // Q fragments hoisted (pre-scaled)
    short8 aq0 = *(const short8*)&Qg[(size_t)(l0 + w * 16 + c) * 64 + g * 8];
    short8 aq1 = *(const short8*)&Qg[(size_t)(l0 + w * 16 + c) * 64 + 32 + g * 8];

    // QD-gather constants (tile-invariant)
    int bpa[4];
    bool selb[4];
#pragma unroll
    for (int i = 0; i < 4; i++) {
        int cp = (g * 4 + i - c + 15) & 15;
        bpa[i] = (g * 16 + cp) * 4;
        selb[i] = (g * 4 + i) > c;
    }

    float s_part[4];
    f32x4 acc_o[4];
#pragma unroll
    for (int i = 0; i < 4; i++) { s_part[i] = 0.f; acc_o[i] = (f32x4)0.f; }

    for (int r0 = 0; r0 < 512; r0 += 64) {
        const int pbase = l0 - r0 + 448;        // dist window start in [0, 896]
        __syncthreads();                        // (1) prev-tile KD/P/PV reads done

        // stage K (2 glls) + dist window (4 glls)
        GLL16(Kg + (size_t)(r0 + w * 16) * 64 + lane * 8,     KsU + (w * 16) * 64 + lane * 8);
        GLL16(Kg + (size_t)(r0 + w * 16 + 8) * 64 + lane * 8, KsU + (w * 16 + 8) * 64 + lane * 8);
        const unsigned short* dsrc = dists + (size_t)pbase * 64;
#pragma unroll
        for (int j = 0; j < 4; j++)
            GLL16(dsrc + (size_t)(w * 32 + j * 8) * 64 + lane * 8,
                  DsU + (w * 32 + j * 8) * 64 + lane * 8);
        // mask (folded into S1 acc init); drained by barrier (2)'s vmcnt
        const float* mrow = mask + (size_t)bk * 512 + r0;
        float mv2[4];
#pragma unroll
        for (int f = 0; f < 4; f++) mv2[f] = mrow[f * 16 + c] * LOG2E;
        __syncthreads();                        // (2) staging visible

        // fragment reads: K (8 b128) and dist (10 b128)
        short8 bkf0[4], bkf1[4];
#pragma unroll
        for (int f = 0; f < 4; f++) {
            bkf0[f] = *(const short8*)&KsU[(f * 16 + c) * 64 + xsw];
            bkf1[f] = *(const short8*)&KsU[(f * 16 + c) * 64 + xsw4];
        }
        short8 dq0[5], dq1[5];
#pragma unroll
        for (int q5 = 0; q5 < 5; q5++) {
            dq0[q5] = *(const short8*)&DsU[((w + q5) * 16 + c) * 64 + xsw];
            dq1[q5] = *(const short8*)&DsU[((w + q5) * 16 + c) * 64 + xsw4];
        }
        __syncthreads();                        // (2b) staging dead -> KDs alias safe

        // S1 = QK^T with mask-init accumulator
        f32x4 s_acc[4];
#pragma unroll
        for (int f = 0; f < 4; f++) {
            f32x4 z = {mv2[f], mv2[f], mv2[f], mv2[f]};
            z = MFMA_BF16(aq0, bkf0[f], z);
            s_acc[f] = MFMA_BF16(aq1, bkf1[f], z);
        }
        // QD: 5 frags, in registers
        f32x4 aQ[5];
#pragma unroll
        for (int q5 = 0; q5 < 5; q5++) {
            f32x4 z = (f32x4)0.f;
            z = MFMA_BF16(aq0, dq0[q5], z);
            aQ[q5] = MFMA_BF16(aq1, dq1[q5], z);
        }
        // KD transposed (f-corrected): band row 16f+c, bucket j from dist frag
        // (3-f+j) at compact col (w+j)*16 -> read col recovers rel row for all f.
#pragma unroll
        for (int f = 0; f < 4; f++)
#pragma unroll
            for (int j = 0; j < 2; j++) {
                const int q = 3 - f + j;
                f32x4 aK = (f32x4)0.f;
                aK = MFMA_BF16(dq0[q], bkf0[f], aK);
                aK = MFMA_BF16(dq1[q], bkf1[f], aK);
                *(f32x4*)&KDs[(16 * f + c) * 84 + (w + j) * 16 + g * 4] = aK;
            }

        // V loads (global, consumed in PV -> latency hidden)
        short8 vfr[4][2];
#pragma unroll
        for (int n = 0; n < 4; n++)
#pragma unroll
            for (int j = 0; j < 2; j++)
                vfr[n][j] = *(const short8*)&Vg[(size_t)(n * 16 + c) * 512 + r0 + j * 32 + g * 8];

        // QD gather: 20 bpermute + cndmask select
        int bp[5][4];
#pragma unroll
        for (int q5 = 0; q5 < 5; q5++)
#pragma unroll
            for (int i = 0; i < 4; i++)
                bp[q5][i] = __builtin_amdgcn_ds_bpermute(bpa[i], __builtin_bit_cast(int, aQ[q5][i]));

        // assembly: exp2(s1 + qd + kd), accumulate denominator
        float pv[4][4];
#pragma unroll
        for (int f = 0; f < 4; f++) {
            const float* kdb = &KDs[(16 * f + c) * 84 + w * 16 + g * 4 - c + 15];
#pragma unroll
            for (int i = 0; i < 4; i++) {
                float kd = kdb[i];
                float qd = __builtin_bit_cast(float, selb[i] ? bp[4 - f][i] : bp[3 - f][i]);
                float pe = exp2_fast(s_acc[f][i] + qd + kd);
                pv[f][i] = pe;
                s_part[i] += pe;
            }
        }
        // P -> LDS (own rows only)
#pragma unroll
        for (int f = 0; f < 4; f += 2)
#pragma unroll
            for (int i = 0; i < 4; i++) {
                unsigned pk2 = cvt_pk_bf16(pv[f][i], pv[f + 1][i]);
                const int row = (w * 16 + g * 4 + i) * 76;
                Ps[row + f * 16 + c] = (unsigned short)pk2;
                Ps[row + (f + 1) * 16 + c] = (unsigned short)(pk2 >> 16);
            }

        // O += P V
#pragma unroll
        for (int j = 0; j < 2; j++) {
            short8 ap = *(const short8*)&Ps[(w * 16 + c) * 76 + j * 32 + g * 8];
#pragma unroll
            for (int n = 0; n < 4; n++)
                acc_o[n] = MFMA_BF16(ap, vfr[n][j], acc_o[n]);
        }
    }

    // finalize: cross-lane denom reduce, then ctx[bk][l][h*64+d] = O/s
#pragma unroll
    for (int off = 1; off < 16; off <<= 1)
#pragma unroll
        for (int i = 0; i < 4; i++) s_part[i] += __shfl_xor(s_part[i], off);
#pragma unroll
    for (int i = 0; i < 4; i++) {
        float inv = 1.0f / s_part[i];
        int ll = w * 16 + g * 4 + i;
        unsigned short* dst = ctxb + ((size_t)bk * 512 + l0 + ll) * 1024 + h * 64;
#pragma unroll
        for (int n = 0; n < 4; n++) dst[n * 16 + c] = f2bf(acc_o[n][i] * inv);
    }
}

// ---------------------------------------------------------------- average over k (bf16)
__global__ void avg_kernel(const unsigned short* __restrict__ ctx, unsigned short* __restrict__ avgb) {
    int i = blockIdx.x * 256 + threadIdx.x;     // ushort4 index over [2048][256]
    if (i >= 2048 * 256) return;
    int e4 = i & 255, bl = i >> 8;
    int b = bl >> 9, l = bl & 511;
    size_t base = ((size_t)(b * 4) * 512 + l) * 256 + e4;
    const ushort4* cv = (const ushort4*)ctx;
    float s0 = 0.f, s1 = 0.f, s2 = 0.f, s3 = 0.f;
#pragma unroll
    for (int j = 0; j < 4; j++) {
        ushort4 v = cv[base + (size_t)j * 512 * 256];
        s0 += bf2f(v.x); s1 += bf2f(v.y); s2 += bf2f(v.z); s3 += bf2f(v.w);
    }
    ushort4 o;
    o.x = f2bf(s0 * 0.25f); o.y = f2bf(s1 * 0.25f);
    o.z = f2bf(s2 * 0.25f); o.w = f2bf(s3 * 0.25f);
    ((ushort4*)avgb)[i] = o;
}

// ---------------------------------------------------------------- LayerNorm rows of 1024 (in-place)
__global__ __launch_bounds__(256) void ln_kernel(float* __restrict__ x,
                                                 const float* __restrict__ gamma,
                                                 const float* __restrict__ beta) {
    const int row = blockIdx.x, t = threadIdx.x;
    float* xr = x + (size_t)row * 1024;
    float v[4], s = 0.f, sq = 0.f;
#pragma unroll
    for (int j = 0; j < 4; j++) { v[j] = xr[t + j * 256]; s += v[j]; sq += v[j] * v[j]; }
#pragma unroll
    for (int off = 1; off < 64; off <<= 1) { s += __shfl_xor(s, off); sq += __shfl_xor(sq, off); }
    __shared__ float ss[4], ssq[4];
    if ((t & 63) == 0) { ss[t >> 6] = s; ssq[t >> 6] = sq; }
    __syncthreads();
    s = ss[0] + ss[1] + ss[2] + ss[3];
    sq = ssq[0] + ssq[1] + ssq[2] + ssq[3];
    float mu = s * (1.f / 1024.f);
    float var = fmaxf(sq * (1.f / 1024.f) - mu * mu, 0.f);
    float inv = 1.0f / sqrtf(var + 1e-12f);
#pragma unroll
    for (int j = 0; j < 4; j++) {
        int e = t + j * 256;
        xr[e] = gamma[e] * (v[j] - mu) * inv + beta[e];
    }
}

// ---------------------------------------------------------------- launch
extern "C" void kernel_launch(void* const* d_in, const int* in_sizes, int n_in,
                              void* d_out, int out_size, void* d_ws, size_t ws_size,
                              hipStream_t stream) {
    const float* hs    = (const float*)d_in[0];
    const float* inj   = (const float*)d_in[1];
    const float* maskp = (const float*)d_in[2];
    const float* Wq    = (const float*)d_in[3];
    const float* bq    = (const float*)d_in[4];
    const float* Wk    = (const float*)d_in[5];
    const float* bk_   = (const float*)d_in[6];
    const float* Wv    = (const float*)d_in[7];
    const float* bv    = (const float*)d_in[8];
    const float* de    = (const float*)d_in[9];
    const float* Wo    = (const float*)d_in[10];
    const float* bo    = (const float*)d_in[11];
    const float* ln_g  = (const float*)d_in[12];
    const float* ln_b  = (const float*)d_in[13];
    float* out = (float*)d_out;
    (void)in_sizes; (void)n_in; (void)out_size; (void)ws_size;

    unsigned char* p = (unsigned char*)d_ws;
    auto take = [&](size_t bytes) {
        unsigned char* r = p;
        p += (bytes + 255) & ~(size_t)255;
        return r;
    };
    unsigned short* hsb   = (unsigned short*)take(2048ull * 1024 * 2);
    unsigned short* injb  = (unsigned short*)take(8192ull * 1024 * 2);
    unsigned short* Wqb   = (unsigned short*)take(1024ull * 1024 * 2);
    unsigned short* Wkb   = (unsigned short*)take(1024ull * 1024 * 2);
    unsigned short* Wvb   = (unsigned short*)take(1024ull * 1024 * 2);
    unsigned short* Wob   = (unsigned short*)take(1024ull * 1024 * 2);
    unsigned short* dists = (unsigned short*)take(1024ull * 64 * 2);   // row 1023 = pad
    unsigned short* Qbuf  = (unsigned short*)take(4ull * 16 * 512 * 64 * 2);
    unsigned short* Kbufs = (unsigned short*)take(16ull * 16 * 512 * 64 * 2);
    unsigned short* Vtb   = (unsigned short*)take(16ull * 16 * 64 * 512 * 2);
    unsigned short* ctxb  = (unsigned short*)take(16ull * 512 * 1024 * 2);
    unsigned short* avgb  = (unsigned short*)take(2048ull * 1024 * 2);

    // fused f32 -> bf16 converts (dist swizzled + sqrt(beta)-scaled)
    CvtArgs ca;
    ca.s[0] = hs;  ca.d[0] = hsb;   ca.n4[0] = 2048 * 256; ca.scale[0] = 1.f;
    ca.s[1] = inj; ca.d[1] = injb;  ca.n4[1] = 8192 * 256; ca.scale[1] = 1.f;
    ca.s[2] = Wq;  ca.d[2] = Wqb;   ca.n4[2] = 1024 * 256; ca.scale[2] = 1.f;
    ca.s[3] = Wk;  ca.d[3] = Wkb;   ca.n4[3] = 1024 * 256; ca.scale[3] = 1.f;
    ca.s[4] = Wv;  ca.d[4] = Wvb;   ca.n4[4] = 1024 * 256; ca.scale[4] = 1.f;
    ca.s[5] = Wo;  ca.d[5] = Wob;   ca.n4[5] = 1024 * 256; ca.scale[5] = 1.f;
    ca.s[6] = de;  ca.d[6] = dists; ca.n4[6] = 1023 * 16;  ca.scale[6] = SQRT_BETA;
    cvt_all<<<2048, 256, 0, stream>>>(ca);

    // Q+K+V projections: three single-acc 128^2 GEMM paths, 3 blocks/CU
    gemm_qkv<<<dim3(144, 8), 256, 0, stream>>>(injb, hsb, Wkb, Wvb, Wqb,
                                               bk_, bv, bq, Kbufs, Vtb, Qbuf);

    // attention (r13 proven optimum)
    attn_kernel<<<2048, 256, 0, stream>>>(Qbuf, Kbufs, Vtb, dists, maskp, ctxb);

    // average over k candidates
    avg_kernel<<<2048, 256, 0, stream>>>(ctxb, avgb);

    // output projection + bias + residual, then LayerNorm in-place on d_out
    gemm128<<<dim3(16, 8), 256, 0, stream>>>(avgb, Wob, bo, hs, out);
    ln_kernel<<<2048, 256, 0, stream>>>(out, ln_g, ln_b);
}